// Round 14
// baseline (343.527 us; speedup 1.0000x reference)
//
#include <hip/hip_runtime.h>
#include <hip/hip_fp16.h>
#include <math.h>

#define N_NODES 50000
#define N_EDGES 800000
#define NEG_SLOPE 0.2f

#define BKT_SHIFT 7
#define N_BKT 512                      // pow2 upper bound; used: ceil(50000/128)=391
#define CHUNK 2048                     // edges per phase-A block
#define NB_SCAT ((N_EDGES + CHUNK - 1) / CHUNK)   // 391
#define PACK_ELEMS 81920
#define PACK_BLOCKS ((PACK_ELEMS + 511) / 512)    // 160
#define BCAP 4096                      // fixed bucket capacity (mean 2048, 45 sigma)
#define PB_CAP 4096
#define CSR_PAD 64                     // zero tail so fused_gat prefetch needs no clamps

typedef _Float16 v8h __attribute__((ext_vector_type(8)));
typedef _Float16 h4  __attribute__((ext_vector_type(4)));
typedef _Float16 h2  __attribute__((ext_vector_type(2)));
typedef float f32x4 __attribute__((ext_vector_type(4)));
typedef float f32x2 __attribute__((ext_vector_type(2)));

static inline int cdiv(long long a, int b) { return (int)((a + b - 1) / b); }

// ===== Phase A: LDS bucket sort per 2048-edge chunk + (merged) weight packing =====
__global__ __launch_bounds__(512) void bucket_scatter(const int* __restrict__ esrc,
                                                      const int* __restrict__ edst,
                                                      int* __restrict__ bcnt,
                                                      int2* __restrict__ tmp,
                                                      const float* __restrict__ W1l,
                                                      const float* __restrict__ W1r,
                                                      const float* __restrict__ W2l,
                                                      const float* __restrict__ W2r,
                                                      const float* __restrict__ W3l,
                                                      const float* __restrict__ W3r,
                                                      _Float16* __restrict__ Wt1,
                                                      _Float16* __restrict__ Wt2,
                                                      _Float16* __restrict__ Wt3) {
    // -------- merged weight-packing blocks (uniform per block; no barriers crossed) -----
    if (blockIdx.x >= NB_SCAT) {
        int id = (blockIdx.x - NB_SCAT) * 512 + threadIdx.x;
        if (id < 32768) {                       // Wt1: [256][128]
            int n = id >> 7, k = id & 127;
            Wt1[id] = (_Float16)(n < 128 ? W1l[k * 128 + n] : W1r[k * 128 + n - 128]);
        } else if (id < 65536) {                // Wt2: [256][128]
            int j = id - 32768; int n = j >> 7, k = j & 127;
            Wt2[j] = (_Float16)(n < 128 ? W2l[k * 128 + n] : W2r[k * 128 + n - 128]);
        } else if (id < 81920) {                // Wt3: [128][128]
            int j = id - 65536; int n = j >> 7, k = j & 127;
            Wt3[j] = (_Float16)(n < 64 ? W3l[k * 64 + n] : W3r[k * 64 + n - 64]);
        }
        return;
    }
    // -------- bucket-scatter blocks --------
    __shared__ int lhist[N_BKT];
    __shared__ int lscan[N_BKT];
    __shared__ int lofs[N_BKT];
    __shared__ int lcur[N_BKT];
    __shared__ int gbase[N_BKT];
    __shared__ int2 lpair[CHUNK];
    int tid = threadIdx.x;
    int base_e = blockIdx.x * CHUNK;
    int count = min(CHUNK, N_EDGES - base_e);

    if (tid < N_BKT) lhist[tid] = 0;
    __syncthreads();

    int e0 = base_e + tid * 4;
    int4 s4 = {0, 0, 0, 0}, d4 = {0, 0, 0, 0};
    int nmine = 0;
    if (e0 + 3 < N_EDGES && e0 + 3 < base_e + count) {
        s4 = *(const int4*)(esrc + e0);
        d4 = *(const int4*)(edst + e0);
        nmine = 4;
    } else if (e0 < N_EDGES) {
        nmine = min(N_EDGES - e0, 4);
        const int* sp = esrc + e0;
        const int* dp = edst + e0;
        if (nmine > 0) { s4.x = sp[0]; d4.x = dp[0]; }
        if (nmine > 1) { s4.y = sp[1]; d4.y = dp[1]; }
        if (nmine > 2) { s4.z = sp[2]; d4.z = dp[2]; }
    }
    int ds[4] = {d4.x, d4.y, d4.z, d4.w};
    int ss[4] = {s4.x, s4.y, s4.z, s4.w};
#pragma unroll
    for (int u = 0; u < 4; ++u)
        if (u < nmine) atomicAdd(&lhist[ds[u] >> BKT_SHIFT], 1);
    __syncthreads();

    // exclusive scan over N_BKT in LDS (Hillis-Steele, 512 threads = N_BKT)
    int v = lhist[tid];
    lscan[tid] = v;
    __syncthreads();
    for (int st = 1; st < N_BKT; st <<= 1) {
        int t = (tid >= st) ? lscan[tid - st] : 0;
        __syncthreads();
        lscan[tid] += t;
        __syncthreads();
    }
    {
        int excl = lscan[tid] - v;
        lofs[tid] = excl;
        lcur[tid] = excl;
        if (v > 0) gbase[tid] = tid * BCAP + atomicAdd(&bcnt[tid], v);
    }
    __syncthreads();

    // place into LDS, bucket-sorted
#pragma unroll
    for (int u = 0; u < 4; ++u)
        if (u < nmine) {
            int b = ds[u] >> BKT_SHIFT;
            int p = atomicAdd(&lcur[b], 1);
            lpair[p] = make_int2(ss[u], ds[u]);
        }
    __syncthreads();

    // linear writeout: adjacent j -> adjacent slots within bucket runs (coalesced)
    for (int j = tid; j < count; j += 512) {
        int2 pr = lpair[j];
        int b = pr.y >> BKT_SHIFT;
        int idx = gbase[b] + (j - lofs[b]);
        if (idx < (b + 1) * BCAP) tmp[idx] = pr;   // 45-sigma overflow guard
    }
}

// ===== Phase B: derive per-node degrees from tmp slice; coalesced csr/off writeout =====
__global__ __launch_bounds__(256, 2) void bucket_to_csr(const int* __restrict__ bcnt,
                                                        const int2* __restrict__ tmp,
                                                        int* __restrict__ off,
                                                        int* __restrict__ csr) {
    __shared__ int red[256];
    __shared__ int lcnt[128];
    __shared__ int sc[128];
    __shared__ int loff[129];
    __shared__ int lcur[128];
    __shared__ int lcsr[PB_CAP];
    int tid = threadIdx.x;
    int b = blockIdx.x;
    int d0 = b << BKT_SHIFT;
    int dend = min(d0 + 128, N_NODES);
    int nn = dend - d0;

    if (b == 0 && tid < CSR_PAD) csr[N_EDGES + tid] = 0;   // zero pad: clamp-free prefetch

    // global base = sum bcnt[0 .. b)   (<=391 ints)
    int pre = 0;
    for (int i = tid; i < b; i += 256) pre += bcnt[i];
    red[tid] = pre;
    __syncthreads();
    for (int st = 128; st > 0; st >>= 1) {
        if (tid < st) red[tid] += red[tid + st];
        __syncthreads();
    }
    int base = red[0];
    __syncthreads();

    int n = min(bcnt[b], BCAP);          // edges in this bucket
    int tbase = b * BCAP;

    // pass 1: per-node histogram from tmp slice (L2-hot, ~16 KB)
    if (tid < 128) lcnt[tid] = 0;
    __syncthreads();
    for (int j = tid; j < n; j += 256) {
        int dl = tmp[tbase + j].y - d0;
        atomicAdd(&lcnt[dl], 1);
    }
    __syncthreads();

    // local exclusive scan of lcnt[0..128)
    if (tid < 128) sc[tid] = lcnt[tid];
    __syncthreads();
    for (int st = 1; st < 128; st <<= 1) {
        int t = (tid < 128 && tid >= st) ? sc[tid - st] : 0;
        __syncthreads();
        if (tid < 128) sc[tid] += t;
        __syncthreads();
    }
    if (tid < 128) loff[tid + 1] = sc[tid];
    if (tid == 0) loff[0] = 0;
    if (tid < 128) lcur[tid] = 0;
    __syncthreads();

    // off segment (coalesced)
    if (tid < nn) off[d0 + tid] = base + loff[tid];
    if (tid == 0 && dend == N_NODES) off[N_NODES] = base + loff[nn];

    // pass 2: place into LDS staging, then coalesced csr writeout
    for (int j = tid; j < n; j += 256) {
        int2 pr = tmp[tbase + j];
        int dl = pr.y - d0;
        int r = atomicAdd(&lcur[dl], 1);
        int pos = loff[dl] + r;
        if (pos < PB_CAP) lcsr[pos] = pr.x;
    }
    __syncthreads();
    for (int j = tid; j < n; j += 256) csr[base + j] = lcsr[j];
}

// ===== MFMA GEMM: C[M][NT](f16) = A[M][128] @ Bt[NT][128]^T; A is f32 or f16 =====
template<int NT, typename AT>
__global__ __launch_bounds__(256, 3) void gemm_xlr(const AT* __restrict__ A,
                                                   const _Float16* __restrict__ Bt,
                                                   _Float16* __restrict__ C) {
    int w = threadIdx.x >> 6, lane = threadIdx.x & 63;
    int m0 = blockIdx.x * 128 + (w & 1) * 64;
    int n0 = blockIdx.y * 128 + (w >> 1) * 64;
    int q = lane >> 4, li = lane & 15;
    f32x4 acc[4][4] = {};
    const AT* Ap[4];
#pragma unroll
    for (int a = 0; a < 4; ++a) {
        int row = m0 + 16 * a + li;
        if (row > N_NODES - 1) row = N_NODES - 1;  // clamp: no OOB reads
        Ap[a] = A + (size_t)row * 128 + q * 8;
    }
    const _Float16* Bp = Bt + (size_t)(n0 + li) * 128 + q * 8;
#pragma unroll
    for (int kt = 0; kt < 4; ++kt) {
        v8h af[4], bf[4];
#pragma unroll
        for (int a = 0; a < 4; ++a) {
            if constexpr (sizeof(AT) == 4) {
                float4 lo = *(const float4*)(Ap[a] + kt * 32);
                float4 hi = *(const float4*)(Ap[a] + kt * 32 + 4);
                v8h t;
                t[0] = (_Float16)lo.x; t[1] = (_Float16)lo.y; t[2] = (_Float16)lo.z; t[3] = (_Float16)lo.w;
                t[4] = (_Float16)hi.x; t[5] = (_Float16)hi.y; t[6] = (_Float16)hi.z; t[7] = (_Float16)hi.w;
                af[a] = t;
            } else {
                af[a] = *(const v8h*)(Ap[a] + kt * 32);
            }
        }
#pragma unroll
        for (int b = 0; b < 4; ++b) bf[b] = *(const v8h*)(Bp + (size_t)(16 * b) * 128 + kt * 32);
#pragma unroll
        for (int a = 0; a < 4; ++a)
#pragma unroll
            for (int b = 0; b < 4; ++b)
                acc[a][b] = __builtin_amdgcn_mfma_f32_16x16x32_f16(bf[b], af[a], acc[a][b], 0, 0, 0);
    }
    // D[reg r, lane(q,li)] = C[m0+16a+li][n0+16b+4q+r]
#pragma unroll
    for (int a = 0; a < 4; ++a) {
        int m = m0 + 16 * a + li;
        if (m < N_NODES) {
#pragma unroll
            for (int b = 0; b < 4; ++b) {
                h4 t;
                t[0] = (_Float16)acc[a][b][0]; t[1] = (_Float16)acc[a][b][1];
                t[2] = (_Float16)acc[a][b][2]; t[3] = (_Float16)acc[a][b][3];
                *(h4*)(C + (size_t)m * NT + n0 + 16 * b + 4 * q) = t;
            }
        }
    }
}

// ========== fused GATv2: VEC=8, f32x2-packed, depth-3 prefetch, clamp-free (csr pad) ==========
// VEC=16 spills at >=6 waves/EU (R11: 275MB scratch) — keep VEC=8 @ 8 waves/EU.
template<int HOUT, typename OUT_T>
__global__ __launch_bounds__(256, 8) void fused_gat(
    const _Float16* __restrict__ XLR,   // [N][2*HOUT] = [xl | xr]
    const int* __restrict__ off, const int* __restrict__ csr,
    const float* __restrict__ att, const float* __restrict__ bias,
    OUT_T* __restrict__ out) {          // [N][HOUT]
    constexpr int VEC = 8;
    constexpr int LPE = HOUT / VEC;     // lanes per edge (16 or 8)
    constexpr int EPW = 64 / LPE;       // edge groups per wave (4 or 8)
    constexpr int ST = 2 * HOUT;
    int wave = threadIdx.x >> 6, lane = threadIdx.x & 63;
    int node = blockIdx.x * (blockDim.x >> 6) + wave;
    if (node >= N_NODES) return;
    int g = lane / LPE;
    int lg = lane % LPE;
    int cb = lg * VEC;

    f32x2 at2[4], xr2[4];
#pragma unroll
    for (int j = 0; j < 4; ++j) { at2[j][0] = att[cb + 2 * j]; at2[j][1] = att[cb + 2 * j + 1]; }
    v8h xrh = *(const v8h*)(XLR + (size_t)node * ST + HOUT + cb);
    {
        const h2* x2 = (const h2*)&xrh;
#pragma unroll
        for (int j = 0; j < 4; ++j) { xr2[j][0] = (float)x2[j][0]; xr2[j][1] = (float)x2[j][1]; }
    }

    int eoff = off[node];
    int P = off[node + 1] - eoff + 1;   // position 0 = self-loop, 1..deg = csr edges
    float denom = 0.f;
    f32x2 acc2[4] = {};

    int p = g;
    v8h ah0 = {}, ah1 = {}, ah2 = {};
    if (p < P) {
        int src = (p == 0) ? node : csr[eoff + p - 1];
        ah0 = *(const v8h*)(XLR + (size_t)src * ST + cb);
    }
    if (p + EPW < P) {                   // positions >= EPW are never the self-loop
        int src = csr[eoff + p + EPW - 1];
        ah1 = *(const v8h*)(XLR + (size_t)src * ST + cb);
    }
    if (p + 2 * EPW < P) {
        int src = csr[eoff + p + 2 * EPW - 1];
        ah2 = *(const v8h*)(XLR + (size_t)src * ST + cb);
    }
    while (p < P) {
        v8h ch = ah0;
        ah0 = ah1;
        ah1 = ah2;
        {
            // unclamped prefetch: index < N_EDGES + CSR_PAD (zero pad), value in [0,N)
            int srcf = csr[eoff + p + 3 * EPW - 1];
            ah2 = *(const v8h*)(XLR + (size_t)srcf * ST + cb);
        }
        const h2* c2 = (const h2*)&ch;
        f32x2 a2[4];
        f32x2 sdot = {0.f, 0.f};
#pragma unroll
        for (int j = 0; j < 4; ++j) {
            a2[j][0] = (float)c2[j][0]; a2[j][1] = (float)c2[j][1];
            f32x2 v = a2[j] + xr2[j];
            f32x2 vn = v * NEG_SLOPE;
            f32x2 lv;
            lv[0] = fmaxf(v[0], vn[0]); lv[1] = fmaxf(v[1], vn[1]);
            sdot += at2[j] * lv;
        }
        float s = sdot[0] + sdot[1];
        s += __shfl_xor(s, 1); s += __shfl_xor(s, 2); s += __shfl_xor(s, 4);
        float f = __expf(s);
        denom += f;
        f32x2 f2 = {f, f};
#pragma unroll
        for (int j = 0; j < 4; ++j) acc2[j] += a2[j] * f2;   // v_pk_fma_f32
        p += EPW;
    }
#pragma unroll
    for (int o = LPE; o < 64; o <<= 1) {
#pragma unroll
        for (int j = 0; j < 4; ++j) {
            acc2[j][0] += __shfl_xor(acc2[j][0], o);
            acc2[j][1] += __shfl_xor(acc2[j][1], o);
        }
        denom += __shfl_xor(denom, o);
    }
    if (lane < LPE) {
        float inv = 1.f / denom;
        OUT_T* orow = out + (size_t)node * HOUT + cb;
#pragma unroll
        for (int j = 0; j < 4; ++j) {
#pragma unroll
            for (int t = 0; t < 2; ++t) {
                float r = acc2[j][t] * inv + bias[cb + 2 * j + t];
                r = r > 0.f ? r : (__expf(r) - 1.f);    // elu via fast exp
                orow[2 * j + t] = (OUT_T)r;
            }
        }
    }
}

extern "C" void kernel_launch(void* const* d_in, const int* in_sizes, int n_in,
                              void* d_out, int out_size, void* d_ws, size_t ws_size,
                              hipStream_t stream) {
    const float* x    = (const float*)d_in[0];
    const int*   ei   = (const int*)d_in[1];
    const int*   esrc = ei;
    const int*   edst = ei + N_EDGES;
    const float* W1l = (const float*)d_in[2];
    const float* W1r = (const float*)d_in[3];
    const float* att1= (const float*)d_in[4];
    const float* b1  = (const float*)d_in[5];
    const float* W2l = (const float*)d_in[6];
    const float* W2r = (const float*)d_in[7];
    const float* att2= (const float*)d_in[8];
    const float* b2  = (const float*)d_in[9];
    const float* W3l = (const float*)d_in[10];
    const float* W3r = (const float*)d_in[11];
    const float* att3= (const float*)d_in[12];
    const float* b3  = (const float*)d_in[13];
    float* out = (float*)d_out;

    // ---- workspace layout ----
    _Float16* XLR = (_Float16*)d_ws;                    // 50000*256
    _Float16* Hb  = XLR + (size_t)N_NODES * 256;        // 50000*128
    _Float16* Wt1 = Hb + (size_t)N_NODES * 128;         // 256*128
    _Float16* Wt2 = Wt1 + 256 * 128;                    // 256*128
    _Float16* Wt3 = Wt2 + 256 * 128;                    // 128*128
    int* bcnt = (int*)(Wt3 + 128 * 128);                // 512
    int* off  = bcnt + N_BKT;                           // 50001 (+1 pad)
    int* csr  = off + N_NODES + 1 + 1;                  // 800000 + 64 pad
    int2* tmp = (int2*)(csr + N_EDGES + CSR_PAD);       // N_BKT*BCAP int2 = 16.8 MB

    const int TB = 256;

    // ---- CSR build + weight prep ----
    hipMemsetAsync(bcnt, 0, N_BKT * sizeof(int), stream);
    bucket_scatter<<<NB_SCAT + PACK_BLOCKS, 512, 0, stream>>>(
        esrc, edst, bcnt, tmp, W1l, W1r, W2l, W2r, W3l, W3r, Wt1, Wt2, Wt3);
    bucket_to_csr<<<cdiv(N_NODES, 128), 256, 0, stream>>>(bcnt, tmp, off, csr);

    const int WPB = 4;
    int gat_grid = cdiv(N_NODES, WPB);
    dim3 g2(cdiv(N_NODES, 128), 2), g1(cdiv(N_NODES, 128), 1);

    // ---- layer 1 (A = f32 input; cast fused into GEMM) ----
    gemm_xlr<256, float><<<g2, 256, 0, stream>>>(x, Wt1, XLR);
    fused_gat<128, _Float16><<<gat_grid, WPB * 64, 0, stream>>>(XLR, off, csr, att1, b1, Hb);
    // ---- layer 2 ----
    gemm_xlr<256, _Float16><<<g2, 256, 0, stream>>>(Hb, Wt2, XLR);
    fused_gat<128, _Float16><<<gat_grid, WPB * 64, 0, stream>>>(XLR, off, csr, att2, b2, Hb);
    // ---- layer 3 ----
    gemm_xlr<128, _Float16><<<g1, 256, 0, stream>>>(Hb, Wt3, XLR);
    fused_gat<64, float><<<gat_grid, WPB * 64, 0, stream>>>(XLR, off, csr, att3, b3, out);
}

// Round 15
// 303.926 us; speedup vs baseline: 1.1303x; 1.1303x over previous
//
#include <hip/hip_runtime.h>
#include <hip/hip_fp16.h>
#include <math.h>

#define N_NODES 50000
#define N_EDGES 800000
#define NEG_SLOPE 0.2f

#define BKT_SHIFT 7
#define N_BKT 512                      // pow2 upper bound; used: ceil(50000/128)=391
#define NB_CSR ((N_NODES + 127) / 128) // 391
#define CHUNK 2048                     // edges per phase-A block
#define BCAP 4096                      // fixed bucket capacity (mean 2048, 45 sigma)
#define PB_CAP 4096
#define G1_BLOCKS (((N_NODES + 127) / 128) * 2)   // 782 gemm-1 blocks (2 n-tiles)

typedef _Float16 v8h __attribute__((ext_vector_type(8)));
typedef _Float16 h4  __attribute__((ext_vector_type(4)));
typedef _Float16 h2  __attribute__((ext_vector_type(2)));
typedef float f32x4 __attribute__((ext_vector_type(4)));
typedef float f32x2 __attribute__((ext_vector_type(2)));

static inline int cdiv(long long a, int b) { return (int)((a + b - 1) / b); }

// ========= weight packing W[K][N] f32 -> Wt[N][K] f16, plus bcnt zero-init =========
__global__ void pack_weights_zero(const float* __restrict__ W1l, const float* __restrict__ W1r,
                                  const float* __restrict__ W2l, const float* __restrict__ W2r,
                                  const float* __restrict__ W3l, const float* __restrict__ W3r,
                                  _Float16* __restrict__ Wt1, _Float16* __restrict__ Wt2,
                                  _Float16* __restrict__ Wt3, int* __restrict__ bcnt) {
    int id = blockIdx.x * blockDim.x + threadIdx.x;
    if (id < 32768) {                       // Wt1: [256][128]
        int n = id >> 7, k = id & 127;
        Wt1[id] = (_Float16)(n < 128 ? W1l[k * 128 + n] : W1r[k * 128 + n - 128]);
    } else if (id < 65536) {                // Wt2: [256][128]
        int j = id - 32768; int n = j >> 7, k = j & 127;
        Wt2[j] = (_Float16)(n < 128 ? W2l[k * 128 + n] : W2r[k * 128 + n - 128]);
    } else if (id < 81920) {                // Wt3: [128][128]
        int j = id - 65536; int n = j >> 7, k = j & 127;
        Wt3[j] = (_Float16)(n < 64 ? W3l[k * 64 + n] : W3r[k * 64 + n - 64]);
    } else if (id < 81920 + N_BKT) {
        bcnt[id - 81920] = 0;
    }
}

// ===== Phase A: LDS bucket sort per 2048-edge chunk, coalesced run append =====
__global__ __launch_bounds__(512) void bucket_scatter(const int* __restrict__ esrc,
                                                      const int* __restrict__ edst,
                                                      int* __restrict__ bcnt,
                                                      int2* __restrict__ tmp) {
    __shared__ int lhist[N_BKT];
    __shared__ int lscan[N_BKT];
    __shared__ int lofs[N_BKT];
    __shared__ int lcur[N_BKT];
    __shared__ int gbase[N_BKT];
    __shared__ int2 lpair[CHUNK];
    int tid = threadIdx.x;
    int base_e = blockIdx.x * CHUNK;
    int count = min(CHUNK, N_EDGES - base_e);

    if (tid < N_BKT) lhist[tid] = 0;
    __syncthreads();

    int e0 = base_e + tid * 4;
    int4 s4 = {0, 0, 0, 0}, d4 = {0, 0, 0, 0};
    int nmine = 0;
    if (e0 + 3 < N_EDGES && e0 + 3 < base_e + count) {
        s4 = *(const int4*)(esrc + e0);
        d4 = *(const int4*)(edst + e0);
        nmine = 4;
    } else if (e0 < N_EDGES) {
        nmine = min(N_EDGES - e0, 4);
        const int* sp = esrc + e0;
        const int* dp = edst + e0;
        if (nmine > 0) { s4.x = sp[0]; d4.x = dp[0]; }
        if (nmine > 1) { s4.y = sp[1]; d4.y = dp[1]; }
        if (nmine > 2) { s4.z = sp[2]; d4.z = dp[2]; }
    }
    int ds[4] = {d4.x, d4.y, d4.z, d4.w};
    int ss[4] = {s4.x, s4.y, s4.z, s4.w};
#pragma unroll
    for (int u = 0; u < 4; ++u)
        if (u < nmine) atomicAdd(&lhist[ds[u] >> BKT_SHIFT], 1);
    __syncthreads();

    // exclusive scan over N_BKT in LDS (Hillis-Steele, 512 threads = N_BKT)
    int v = lhist[tid];
    lscan[tid] = v;
    __syncthreads();
    for (int st = 1; st < N_BKT; st <<= 1) {
        int t = (tid >= st) ? lscan[tid - st] : 0;
        __syncthreads();
        lscan[tid] += t;
        __syncthreads();
    }
    {
        int excl = lscan[tid] - v;
        lofs[tid] = excl;
        lcur[tid] = excl;
        if (v > 0) gbase[tid] = tid * BCAP + atomicAdd(&bcnt[tid], v);
    }
    __syncthreads();

#pragma unroll
    for (int u = 0; u < 4; ++u)
        if (u < nmine) {
            int b = ds[u] >> BKT_SHIFT;
            int p = atomicAdd(&lcur[b], 1);
            lpair[p] = make_int2(ss[u], ds[u]);
        }
    __syncthreads();

    for (int j = tid; j < count; j += 512) {
        int2 pr = lpair[j];
        int b = pr.y >> BKT_SHIFT;
        int idx = gbase[b] + (j - lofs[b]);
        if (idx < (b + 1) * BCAP) tmp[idx] = pr;   // 45-sigma overflow guard
    }
}

// ===== Merged dispatch: blocks [0,391) finalize CSR; blocks [391, 391+782) run layer-1 GEMM =====
// Independent work items; both complete before fused_gat layer 1. Saves a launch gap and
// overlaps csr LDS-ranking with MFMA.
__global__ __launch_bounds__(256, 2) void csr_and_gemm1(const int* __restrict__ bcnt,
                                                        const int2* __restrict__ tmp,
                                                        int* __restrict__ off,
                                                        int* __restrict__ csr,
                                                        const float* __restrict__ A,
                                                        const _Float16* __restrict__ Bt,
                                                        _Float16* __restrict__ C) {
    __shared__ int red[256];
    __shared__ int lcnt[128];
    __shared__ int sc[128];
    __shared__ int loff[129];
    __shared__ int lcur[128];
    __shared__ int lcsr[PB_CAP];
    int tid = threadIdx.x;

    if (blockIdx.x >= NB_CSR) {
        // ---------------- layer-1 GEMM part (A = f32 input, cast in-register) ------------
        int gb = blockIdx.x - NB_CSR;
        int bx = gb % NB_CSR;
        int by = gb / NB_CSR;           // 0 or 1
        int w = tid >> 6, lane = tid & 63;
        int m0 = bx * 128 + (w & 1) * 64;
        int n0 = by * 128 + (w >> 1) * 64;
        int q = lane >> 4, li = lane & 15;
        f32x4 acc[4][4] = {};
        const float* Ap[4];
#pragma unroll
        for (int a = 0; a < 4; ++a) {
            int row = m0 + 16 * a + li;
            if (row > N_NODES - 1) row = N_NODES - 1;
            Ap[a] = A + (size_t)row * 128 + q * 8;
        }
        const _Float16* Bp = Bt + (size_t)(n0 + li) * 128 + q * 8;
#pragma unroll
        for (int kt = 0; kt < 4; ++kt) {
            v8h af[4], bf[4];
#pragma unroll
            for (int a = 0; a < 4; ++a) {
                float4 lo = *(const float4*)(Ap[a] + kt * 32);
                float4 hi = *(const float4*)(Ap[a] + kt * 32 + 4);
                v8h t;
                t[0] = (_Float16)lo.x; t[1] = (_Float16)lo.y; t[2] = (_Float16)lo.z; t[3] = (_Float16)lo.w;
                t[4] = (_Float16)hi.x; t[5] = (_Float16)hi.y; t[6] = (_Float16)hi.z; t[7] = (_Float16)hi.w;
                af[a] = t;
            }
#pragma unroll
            for (int b = 0; b < 4; ++b) bf[b] = *(const v8h*)(Bp + (size_t)(16 * b) * 128 + kt * 32);
#pragma unroll
            for (int a = 0; a < 4; ++a)
#pragma unroll
                for (int b = 0; b < 4; ++b)
                    acc[a][b] = __builtin_amdgcn_mfma_f32_16x16x32_f16(bf[b], af[a], acc[a][b], 0, 0, 0);
        }
#pragma unroll
        for (int a = 0; a < 4; ++a) {
            int m = m0 + 16 * a + li;
            if (m < N_NODES) {
#pragma unroll
                for (int b = 0; b < 4; ++b) {
                    h4 t;
                    t[0] = (_Float16)acc[a][b][0]; t[1] = (_Float16)acc[a][b][1];
                    t[2] = (_Float16)acc[a][b][2]; t[3] = (_Float16)acc[a][b][3];
                    *(h4*)(C + (size_t)m * 256 + n0 + 16 * b + 4 * q) = t;
                }
            }
        }
        return;
    }

    // ---------------- CSR finalize part ----------------
    int b = blockIdx.x;
    int d0 = b << BKT_SHIFT;
    int dend = min(d0 + 128, N_NODES);
    int nn = dend - d0;

    int pre = 0;
    for (int i = tid; i < b; i += 256) pre += bcnt[i];
    red[tid] = pre;
    __syncthreads();
    for (int st = 128; st > 0; st >>= 1) {
        if (tid < st) red[tid] += red[tid + st];
        __syncthreads();
    }
    int base = red[0];
    __syncthreads();

    int n = min(bcnt[b], BCAP);
    int tbase = b * BCAP;

    if (tid < 128) lcnt[tid] = 0;
    __syncthreads();
    for (int j = tid; j < n; j += 256) {
        int dl = tmp[tbase + j].y - d0;
        atomicAdd(&lcnt[dl], 1);
    }
    __syncthreads();

    if (tid < 128) sc[tid] = lcnt[tid];
    __syncthreads();
    for (int st = 1; st < 128; st <<= 1) {
        int t = (tid < 128 && tid >= st) ? sc[tid - st] : 0;
        __syncthreads();
        if (tid < 128) sc[tid] += t;
        __syncthreads();
    }
    if (tid < 128) loff[tid + 1] = sc[tid];
    if (tid == 0) loff[0] = 0;
    if (tid < 128) lcur[tid] = 0;
    __syncthreads();

    if (tid < nn) off[d0 + tid] = base + loff[tid];
    if (tid == 0 && dend == N_NODES) off[N_NODES] = base + loff[nn];

    for (int j = tid; j < n; j += 256) {
        int2 pr = tmp[tbase + j];
        int dl = pr.y - d0;
        int r = atomicAdd(&lcur[dl], 1);
        int pos = loff[dl] + r;
        if (pos < PB_CAP) lcsr[pos] = pr.x;
    }
    __syncthreads();
    for (int j = tid; j < n; j += 256) csr[base + j] = lcsr[j];
}

// ===== MFMA GEMM (layers 2,3): C[M][NT](f16) = A[M][128] @ Bt[NT][128]^T =====
template<int NT>
__global__ __launch_bounds__(256, 3) void gemm_xlr(const _Float16* __restrict__ A,
                                                   const _Float16* __restrict__ Bt,
                                                   _Float16* __restrict__ C) {
    int w = threadIdx.x >> 6, lane = threadIdx.x & 63;
    int m0 = blockIdx.x * 128 + (w & 1) * 64;
    int n0 = blockIdx.y * 128 + (w >> 1) * 64;
    int q = lane >> 4, li = lane & 15;
    f32x4 acc[4][4] = {};
    const _Float16* Ap[4];
#pragma unroll
    for (int a = 0; a < 4; ++a) {
        int row = m0 + 16 * a + li;
        if (row > N_NODES - 1) row = N_NODES - 1;  // clamp: no OOB reads
        Ap[a] = A + (size_t)row * 128 + q * 8;
    }
    const _Float16* Bp = Bt + (size_t)(n0 + li) * 128 + q * 8;
#pragma unroll
    for (int kt = 0; kt < 4; ++kt) {
        v8h af[4], bf[4];
#pragma unroll
        for (int a = 0; a < 4; ++a) af[a] = *(const v8h*)(Ap[a] + kt * 32);
#pragma unroll
        for (int b = 0; b < 4; ++b) bf[b] = *(const v8h*)(Bp + (size_t)(16 * b) * 128 + kt * 32);
#pragma unroll
        for (int a = 0; a < 4; ++a)
#pragma unroll
            for (int b = 0; b < 4; ++b)
                acc[a][b] = __builtin_amdgcn_mfma_f32_16x16x32_f16(bf[b], af[a], acc[a][b], 0, 0, 0);
    }
#pragma unroll
    for (int a = 0; a < 4; ++a) {
        int m = m0 + 16 * a + li;
        if (m < N_NODES) {
#pragma unroll
            for (int b = 0; b < 4; ++b) {
                h4 t;
                t[0] = (_Float16)acc[a][b][0]; t[1] = (_Float16)acc[a][b][1];
                t[2] = (_Float16)acc[a][b][2]; t[3] = (_Float16)acc[a][b][3];
                *(h4*)(C + (size_t)m * NT + n0 + 16 * b + 4 * q) = t;
            }
        }
    }
}

// ========== fused GATv2 (R13-proven): VEC=8, f32x2-packed, depth-2 CLAMPED prefetch ==========
// Depth-3/unclamped regressed (R14: +44MB FETCH from prefetch overrun into other nodes' rows).
// VEC=16 spills at >=6 waves/EU (R11). Keep VEC=8 @ 8 waves/EU, clamped prefetch.
template<int HOUT, typename OUT_T>
__global__ __launch_bounds__(256, 8) void fused_gat(
    const _Float16* __restrict__ XLR,   // [N][2*HOUT] = [xl | xr]
    const int* __restrict__ off, const int* __restrict__ csr,
    const float* __restrict__ att, const float* __restrict__ bias,
    OUT_T* __restrict__ out) {          // [N][HOUT]
    constexpr int VEC = 8;
    constexpr int LPE = HOUT / VEC;     // lanes per edge (16 or 8)
    constexpr int EPW = 64 / LPE;       // edge groups per wave (4 or 8)
    constexpr int ST = 2 * HOUT;
    int wave = threadIdx.x >> 6, lane = threadIdx.x & 63;
    int node = blockIdx.x * (blockDim.x >> 6) + wave;
    if (node >= N_NODES) return;
    int g = lane / LPE;
    int lg = lane % LPE;
    int cb = lg * VEC;

    f32x2 at2[4], xr2[4];
#pragma unroll
    for (int j = 0; j < 4; ++j) { at2[j][0] = att[cb + 2 * j]; at2[j][1] = att[cb + 2 * j + 1]; }
    v8h xrh = *(const v8h*)(XLR + (size_t)node * ST + HOUT + cb);
    {
        const h2* x2 = (const h2*)&xrh;
#pragma unroll
        for (int j = 0; j < 4; ++j) { xr2[j][0] = (float)x2[j][0]; xr2[j][1] = (float)x2[j][1]; }
    }

    int eoff = off[node];
    int P = off[node + 1] - eoff + 1;   // position 0 = self-loop, 1..deg = csr edges
    float denom = 0.f;
    f32x2 acc2[4] = {};

    int p = g;
    v8h ah0 = {}, ah1 = {};
    if (p < P) {
        int src = (p == 0) ? node : csr[eoff + p - 1];
        ah0 = *(const v8h*)(XLR + (size_t)src * ST + cb);
    }
    if (p + EPW < P) {                   // prologue depth-2 (p+EPW>0: never self-loop)
        int src = csr[eoff + p + EPW - 1];
        ah1 = *(const v8h*)(XLR + (size_t)src * ST + cb);
    }
    while (p < P) {
        v8h ch = ah0;
        ah0 = ah1;
        {
            int pf = p + 2 * EPW;
            int pc = min(pf, P - 1) - 1;     // clamp: overrun re-reads own last row (cache hit)
            pc = max(pc, 0);
            int srcf = csr[eoff + pc];
            srcf = min(srcf, N_NODES - 1);
            ah1 = *(const v8h*)(XLR + (size_t)srcf * ST + cb);
        }
        const h2* c2 = (const h2*)&ch;
        f32x2 a2[4];
        f32x2 sdot = {0.f, 0.f};
#pragma unroll
        for (int j = 0; j < 4; ++j) {
            a2[j][0] = (float)c2[j][0]; a2[j][1] = (float)c2[j][1];
            f32x2 v = a2[j] + xr2[j];
            f32x2 vn = v * NEG_SLOPE;
            f32x2 lv;
            lv[0] = fmaxf(v[0], vn[0]); lv[1] = fmaxf(v[1], vn[1]);
            sdot += at2[j] * lv;
        }
        float s = sdot[0] + sdot[1];
        s += __shfl_xor(s, 1); s += __shfl_xor(s, 2); s += __shfl_xor(s, 4);
        float f = __expf(s);
        denom += f;
        f32x2 f2 = {f, f};
#pragma unroll
        for (int j = 0; j < 4; ++j) acc2[j] += a2[j] * f2;   // v_pk_fma_f32
        p += EPW;
    }
#pragma unroll
    for (int o = LPE; o < 64; o <<= 1) {
#pragma unroll
        for (int j = 0; j < 4; ++j) {
            acc2[j][0] += __shfl_xor(acc2[j][0], o);
            acc2[j][1] += __shfl_xor(acc2[j][1], o);
        }
        denom += __shfl_xor(denom, o);
    }
    if (lane < LPE) {
        float inv = 1.f / denom;
        OUT_T* orow = out + (size_t)node * HOUT + cb;
#pragma unroll
        for (int j = 0; j < 4; ++j) {
#pragma unroll
            for (int t = 0; t < 2; ++t) {
                float r = acc2[j][t] * inv + bias[cb + 2 * j + t];
                r = r > 0.f ? r : (__expf(r) - 1.f);    // elu via fast exp
                orow[2 * j + t] = (OUT_T)r;
            }
        }
    }
}

extern "C" void kernel_launch(void* const* d_in, const int* in_sizes, int n_in,
                              void* d_out, int out_size, void* d_ws, size_t ws_size,
                              hipStream_t stream) {
    const float* x    = (const float*)d_in[0];
    const int*   ei   = (const int*)d_in[1];
    const int*   esrc = ei;
    const int*   edst = ei + N_EDGES;
    const float* W1l = (const float*)d_in[2];
    const float* W1r = (const float*)d_in[3];
    const float* att1= (const float*)d_in[4];
    const float* b1  = (const float*)d_in[5];
    const float* W2l = (const float*)d_in[6];
    const float* W2r = (const float*)d_in[7];
    const float* att2= (const float*)d_in[8];
    const float* b2  = (const float*)d_in[9];
    const float* W3l = (const float*)d_in[10];
    const float* W3r = (const float*)d_in[11];
    const float* att3= (const float*)d_in[12];
    const float* b3  = (const float*)d_in[13];
    float* out = (float*)d_out;

    // ---- workspace layout ----
    _Float16* XLR = (_Float16*)d_ws;                    // 50000*256
    _Float16* Hb  = XLR + (size_t)N_NODES * 256;        // 50000*128
    _Float16* Wt1 = Hb + (size_t)N_NODES * 128;         // 256*128
    _Float16* Wt2 = Wt1 + 256 * 128;                    // 256*128
    _Float16* Wt3 = Wt2 + 256 * 128;                    // 128*128
    int* bcnt = (int*)(Wt3 + 128 * 128);                // 512
    int* off  = bcnt + N_BKT;                           // 50001 (+1 pad)
    int* csr  = off + N_NODES + 1 + 1;                  // 800000
    int2* tmp = (int2*)(csr + N_EDGES);                 // N_BKT*BCAP int2 = 16.8 MB

    const int TB = 256;

    // ---- CSR build + weight prep; layer-1 GEMM merged with CSR finalize ----
    pack_weights_zero<<<cdiv(81920 + N_BKT, TB), TB, 0, stream>>>(
        W1l, W1r, W2l, W2r, W3l, W3r, Wt1, Wt2, Wt3, bcnt);
    bucket_scatter<<<cdiv(N_EDGES, CHUNK), 512, 0, stream>>>(esrc, edst, bcnt, tmp);
    csr_and_gemm1<<<NB_CSR + G1_BLOCKS, 256, 0, stream>>>(bcnt, tmp, off, csr, x, Wt1, XLR);

    const int WPB = 4;
    int gat_grid = cdiv(N_NODES, WPB);
    dim3 g2(cdiv(N_NODES, 128), 2), g1(cdiv(N_NODES, 128), 1);

    // ---- layer 1 ----
    fused_gat<128, _Float16><<<gat_grid, WPB * 64, 0, stream>>>(XLR, off, csr, att1, b1, Hb);
    // ---- layer 2 ----
    gemm_xlr<256><<<g2, 256, 0, stream>>>(Hb, Wt2, XLR);
    fused_gat<128, _Float16><<<gat_grid, WPB * 64, 0, stream>>>(XLR, off, csr, att2, b2, Hb);
    // ---- layer 3 ----
    gemm_xlr<128><<<g1, 256, 0, stream>>>(Hb, Wt3, XLR);
    fused_gat<64, float><<<gat_grid, WPB * 64, 0, stream>>>(XLR, off, csr, att3, b3, out);
}